// Round 4
// baseline (374.230 us; speedup 1.0000x reference)
//
#include <hip/hip_runtime.h>

#define DD 48
#define TT 512
#define BB 512
#define STRIDE 64   // padded LDS row stride for bp
#define CH 64       // t-steps per emit chunk
#define NV 12       // float4 loads per lane per chunk: 64*48 floats / (64 lanes * 4)

__device__ __forceinline__ float readlane_f(float v, int lane) {
  return __int_as_float(__builtin_amdgcn_readlane(__float_as_int(v), lane));
}

// Tree max+argmax over s[0..47], first-index wins ties (strict > to move right).
__device__ __forceinline__ void tree_argmax48(const float* s, float& best, int& idx) {
  float v1[24]; int x1[24];
#pragma unroll
  for (int k = 0; k < 24; ++k) {
    bool g = s[2 * k + 1] > s[2 * k];
    v1[k] = g ? s[2 * k + 1] : s[2 * k];
    x1[k] = g ? 2 * k + 1 : 2 * k;
  }
  float v2[12]; int x2[12];
#pragma unroll
  for (int k = 0; k < 12; ++k) {
    bool g = v1[2 * k + 1] > v1[2 * k];
    v2[k] = g ? v1[2 * k + 1] : v1[2 * k];
    x2[k] = g ? x1[2 * k + 1] : x1[2 * k];
  }
  float v3[6]; int x3[6];
#pragma unroll
  for (int k = 0; k < 6; ++k) {
    bool g = v2[2 * k + 1] > v2[2 * k];
    v3[k] = g ? v2[2 * k + 1] : v2[2 * k];
    x3[k] = g ? x2[2 * k + 1] : x2[2 * k];
  }
  float v4[3]; int x4[3];
#pragma unroll
  for (int k = 0; k < 3; ++k) {
    bool g = v3[2 * k + 1] > v3[2 * k];
    v4[k] = g ? v3[2 * k + 1] : v3[2 * k];
    x4[k] = g ? x3[2 * k + 1] : x3[2 * k];
  }
  bool g0 = v4[1] > v4[0];
  float vm = g0 ? v4[1] : v4[0];
  int xm = g0 ? x4[1] : x4[0];
  bool g1 = v4[2] > vm;
  best = g1 ? v4[2] : vm;
  idx = g1 ? x4[2] : xm;
}

__global__ __launch_bounds__(64, 1) void crf_viterbi(const float* __restrict__ logits,
                                                     const int* __restrict__ lens,
                                                     const float* __restrict__ trans,
                                                     int* __restrict__ out) {
  const int b = blockIdx.x;
  const int j = threadIdx.x;          // 0..63, lanes 0..47 are live tags
  const int jj = j < DD ? j : DD - 1; // clamp for safe global reads

  __shared__ unsigned char bp[TT * STRIDE];   // 32 KB backpointers
  __shared__ float elds[2][CH * DD];          // 2 x 12 KB emit chunks

  // Transition column j in registers
  float tcol[DD];
#pragma unroll
  for (int i = 0; i < DD; ++i) tcol[i] = trans[i * DD + jj];

  const float* lg = logits + (size_t)b * TT * DD;
  const int L = lens[b];
  const int nchunk = (L + CH - 1) / CH; // chunks of 64 t-steps (rows always in-bounds: nchunk*64 <= 512)

  float alpha = lg[jj]; // alpha0 = logits[b,0,:]

  const float4* src = (const float4*)lg; // 768 float4 per chunk
  float4 st[NV];

  // prologue: chunk 0 -> elds[0]; issue loads for chunk 1
#pragma unroll
  for (int i = 0; i < NV; ++i) st[i] = src[i * 64 + j];
  {
    float4* dst = (float4*)&elds[0][0];
#pragma unroll
    for (int i = 0; i < NV; ++i) dst[i * 64 + j] = st[i];
  }
  if (nchunk > 1) {
#pragma unroll
    for (int i = 0; i < NV; ++i) st[i] = src[768 + i * 64 + j];
  }

  for (int c = 0; c < nchunk; ++c) {
    const int buf = c & 1;
    const float* eb = &elds[buf][0];
    const int base = c * CH;
    const int tb = (c == 0) ? 1 : base;
    const int te = (L < base + CH) ? L : base + CH;

    if (tb < te) {
      float ep = eb[(tb - base) * DD + jj]; // prefetch-1
#pragma unroll 2
      for (int t = tb; t < te; ++t) {
        float e = ep;
        int ns = t + 1 - base; ns = ns > CH - 1 ? CH - 1 : ns; // clamped in-chunk
        ep = eb[ns * DD + jj];

        float s[DD];
#pragma unroll
        for (int i = 0; i < DD; ++i) s[i] = readlane_f(alpha, i) + tcol[i];
        float best; int idx;
        tree_argmax48(s, best, idx);
        alpha = best + e;
        bp[t * STRIDE + j] = (unsigned char)idx;
      }
    }

    if (c + 1 < nchunk) { // write staged chunk c+1 into the other buffer
      float4* dst = (float4*)&elds[buf ^ 1][0];
#pragma unroll
      for (int i = 0; i < NV; ++i) dst[i * 64 + j] = st[i];
    }
    if (c + 2 < nchunk) { // issue loads for chunk c+2
#pragma unroll
      for (int i = 0; i < NV; ++i) st[i] = src[(c + 2) * 768 + i * 64 + j];
    }
  }

  __syncthreads(); // single wave: guarantees LDS writes visible

  // last_tag = argmax_j alpha (uniform on all lanes)
  float af[DD];
#pragma unroll
  for (int i = 0; i < DD; ++i) af[i] = readlane_f(alpha, i);
  float bv; int btag;
  tree_argmax48(af, bv, btag);

  int* ob = out + (size_t)b * TT;
  if (j == 0) ob[L - 1] = btag;

  // Backtrack by function composition: H[j] = tag at time t given final tag j.
  int H = j;
  for (int tt = L - 1; tt >= 1; --tt) {
    int v = bp[tt * STRIDE + jj]; // addr independent of H -> pipelined
    H = __shfl(v, H, 64);         // H' = bp_t[H]
    if (j == btag) ob[tt - 1] = H;
  }

  // zero the padded tail t >= L
  for (int tt = L + j; tt < TT; tt += 64) ob[tt] = 0;
}

extern "C" void kernel_launch(void* const* d_in, const int* in_sizes, int n_in,
                              void* d_out, int out_size, void* d_ws, size_t ws_size,
                              hipStream_t stream) {
  const float* logits = (const float*)d_in[0];
  const int* lens     = (const int*)d_in[1];
  const float* trans  = (const float*)d_in[2];
  int* out            = (int*)d_out;
  (void)in_sizes; (void)n_in; (void)out_size; (void)d_ws; (void)ws_size;
  crf_viterbi<<<BB, 64, 0, stream>>>(logits, lens, trans, out);
}

// Round 5
// 372.199 us; speedup vs baseline: 1.0055x; 1.0055x over previous
//
#include <hip/hip_runtime.h>

#define DD 48
#define TT 512
#define BB 512
#define STRIDE 64   // padded LDS row stride for bp
#define CH 64       // t-steps per emit chunk
#define NISS 12     // global_load_lds issues/chunk: 12 * (64 lanes * 16B) = 12288B = 64*48*4

typedef __attribute__((address_space(3))) unsigned int lds_u32_t;
typedef __attribute__((address_space(1))) unsigned int glb_u32_t;

__device__ __forceinline__ void gload_lds16(const float* g, float* l) {
  // lane i writes 16B at (uniform l) + i*16; reads 16B at per-lane g
  __builtin_amdgcn_global_load_lds((const glb_u32_t*)g, (lds_u32_t*)l, 16, 0, 0);
}

__device__ __forceinline__ float readlane_f(float v, int lane) {
  return __int_as_float(__builtin_amdgcn_readlane(__float_as_int(v), lane));
}

// Tree max+argmax over s[0..47], first-index wins ties (strict > to move right).
__device__ __forceinline__ void tree_argmax48(const float* s, float& best, int& idx) {
  float v1[24]; int x1[24];
#pragma unroll
  for (int k = 0; k < 24; ++k) {
    bool g = s[2 * k + 1] > s[2 * k];
    v1[k] = g ? s[2 * k + 1] : s[2 * k];
    x1[k] = g ? 2 * k + 1 : 2 * k;
  }
  float v2[12]; int x2[12];
#pragma unroll
  for (int k = 0; k < 12; ++k) {
    bool g = v1[2 * k + 1] > v1[2 * k];
    v2[k] = g ? v1[2 * k + 1] : v1[2 * k];
    x2[k] = g ? x1[2 * k + 1] : x1[2 * k];
  }
  float v3[6]; int x3[6];
#pragma unroll
  for (int k = 0; k < 6; ++k) {
    bool g = v2[2 * k + 1] > v2[2 * k];
    v3[k] = g ? v2[2 * k + 1] : v2[2 * k];
    x3[k] = g ? x2[2 * k + 1] : x2[2 * k];
  }
  float v4[3]; int x4[3];
#pragma unroll
  for (int k = 0; k < 3; ++k) {
    bool g = v3[2 * k + 1] > v3[2 * k];
    v4[k] = g ? v3[2 * k + 1] : v3[2 * k];
    x4[k] = g ? x3[2 * k + 1] : x3[2 * k];
  }
  bool g0 = v4[1] > v4[0];
  float vm = g0 ? v4[1] : v4[0];
  int xm = g0 ? x4[1] : x4[0];
  bool g1 = v4[2] > vm;
  best = g1 ? v4[2] : vm;
  idx = g1 ? x4[2] : xm;
}

__global__ __launch_bounds__(64, 1) void crf_viterbi(const float* __restrict__ logits,
                                                     const int* __restrict__ lens,
                                                     const float* __restrict__ trans,
                                                     int* __restrict__ out) {
  const int b = blockIdx.x;
  const int j = threadIdx.x;          // 0..63, lanes 0..47 are live tags
  const int jj = j < DD ? j : DD - 1; // clamp for safe reads

  __shared__ unsigned char bp[TT * STRIDE];   // 32 KB backpointers
  __shared__ float elds[2][CH * DD];          // 2 x 12 KB emit chunks

  // Transition column j in registers
  float tcol[DD];
#pragma unroll
  for (int i = 0; i < DD; ++i) tcol[i] = trans[i * DD + jj];

  const float* lg = logits + (size_t)b * TT * DD;
  const int L = lens[b];
  const int nchunk = (L + CH - 1) / CH; // <= 8; chunk rows always within [0,512)

  float alpha = lg[jj]; // alpha0 = logits[b,0,:]

  // stage chunk c into LDS buffer eb via direct global->LDS DMA (no VGPR round-trip)
  auto stage = [&](float* eb, int c) {
    const float* src = lg + c * (CH * DD) + j * 4;
#pragma unroll
    for (int i = 0; i < NISS; ++i) gload_lds16(src + i * 256, eb + i * 256);
  };

  // prologue: issue chunk 0 and chunk 1
  stage(&elds[0][0], 0);
  if (nchunk > 1) stage(&elds[1][0], 1);

  for (int c = 0; c < nchunk; ++c) {
    asm volatile("s_waitcnt vmcnt(0)" ::: "memory"); // chunk c's DMA complete
    const float* eb = &elds[c & 1][0];
    const int base = c * CH;
    const int tb = (c == 0) ? 1 : base;
    const int te = (L < base + CH) ? L : base + CH;

    if (tb < te) {
      float ep = eb[(tb - base) * DD + jj]; // prefetch-1
#pragma unroll 2
      for (int t = tb; t < te; ++t) {
        float e = ep;
        int ns = t + 1 - base; ns = ns > CH - 1 ? CH - 1 : ns; // clamped in-chunk
        ep = eb[ns * DD + jj];

        float s[DD];
#pragma unroll
        for (int i = 0; i < DD; ++i) s[i] = readlane_f(alpha, i) + tcol[i];
        float best; int idx;
        tree_argmax48(s, best, idx);
        alpha = best + e;
        bp[t * STRIDE + j] = (unsigned char)idx;
      }
    }

    // issue chunk c+2 into the buffer we just finished reading
    if (c + 2 < nchunk) stage(&elds[c & 1][0], c + 2);
  }

  __syncthreads(); // single wave: guarantees LDS writes visible

  // last_tag = argmax_j alpha (uniform on all lanes)
  float af[DD];
#pragma unroll
  for (int i = 0; i < DD; ++i) af[i] = readlane_f(alpha, i);
  float bv; int btag;
  tree_argmax48(af, bv, btag);

  int* ob = out + (size_t)b * TT;
  if (j == 0) ob[L - 1] = btag;

  // Backtrack by function composition: H[j] = tag at time t given final tag j.
  int H = j;
  for (int tt = L - 1; tt >= 1; --tt) {
    int v = bp[tt * STRIDE + jj]; // addr independent of H -> pipelined
    H = __shfl(v, H, 64);         // H' = bp_t[H]
    if (j == btag) ob[tt - 1] = H;
  }

  // zero the padded tail t >= L
  for (int tt = L + j; tt < TT; tt += 64) ob[tt] = 0;
}

extern "C" void kernel_launch(void* const* d_in, const int* in_sizes, int n_in,
                              void* d_out, int out_size, void* d_ws, size_t ws_size,
                              hipStream_t stream) {
  const float* logits = (const float*)d_in[0];
  const int* lens     = (const int*)d_in[1];
  const float* trans  = (const float*)d_in[2];
  int* out            = (int*)d_out;
  (void)in_sizes; (void)n_in; (void)out_size; (void)d_ws; (void)ws_size;
  crf_viterbi<<<BB, 64, 0, stream>>>(logits, lens, trans, out);
}

// Round 6
// 315.581 us; speedup vs baseline: 1.1858x; 1.1794x over previous
//
#include <hip/hip_runtime.h>

#define DD 48
#define TT 512
#define BB 512
#define STRIDE 64  // padded LDS row stride for bp
#define PF 8       // emit prefetch depth == inner unroll

// Value via pure fmax chain (VGPR-only); index via cmp/select off the value path.
// First-index wins ties: strict (r > l) to move right at every node.
__device__ __forceinline__ void tree_argmax48(const float* s, float& best, int& idx) {
  float v1[24]; int x1[24];
#pragma unroll
  for (int k = 0; k < 24; ++k) {
    float l = s[2 * k], r = s[2 * k + 1];
    v1[k] = fmaxf(l, r);
    x1[k] = (r > l) ? 2 * k + 1 : 2 * k;
  }
  float v2[12]; int x2[12];
#pragma unroll
  for (int k = 0; k < 12; ++k) {
    float l = v1[2 * k], r = v1[2 * k + 1];
    v2[k] = fmaxf(l, r);
    x2[k] = (r > l) ? x1[2 * k + 1] : x1[2 * k];
  }
  float v3[6]; int x3[6];
#pragma unroll
  for (int k = 0; k < 6; ++k) {
    float l = v2[2 * k], r = v2[2 * k + 1];
    v3[k] = fmaxf(l, r);
    x3[k] = (r > l) ? x2[2 * k + 1] : x2[2 * k];
  }
  float v4[3]; int x4[3];
#pragma unroll
  for (int k = 0; k < 3; ++k) {
    float l = v3[2 * k], r = v3[2 * k + 1];
    v4[k] = fmaxf(l, r);
    x4[k] = (r > l) ? x3[2 * k + 1] : x3[2 * k];
  }
  float vm = fmaxf(v4[0], v4[1]);
  int xm = (v4[1] > v4[0]) ? x4[1] : x4[0];
  best = fmaxf(vm, v4[2]);
  idx = (v4[2] > vm) ? x4[2] : xm;
}

__global__ __launch_bounds__(64, 1) void crf_viterbi(const float* __restrict__ logits,
                                                     const int* __restrict__ lens,
                                                     const float* __restrict__ trans,
                                                     int* __restrict__ out) {
  const int b = blockIdx.x;
  const int j = threadIdx.x;          // lanes 0..47 are live tags
  const int jj = j < DD ? j : DD - 1; // clamp for safe reads

  __shared__ unsigned char bp[TT * STRIDE];  // 32 KB backpointers
  __shared__ __align__(16) float albc[64];   // alpha broadcast buffer

  // Transition column j in registers
  float tcol[DD];
#pragma unroll
  for (int i = 0; i < DD; ++i) tcol[i] = trans[i * DD + jj];

  const float* lg = logits + (size_t)b * TT * DD;
  const int L = lens[b];

  float alpha = lg[jj]; // alpha0

  // 8-deep emit rotation (R3 scheme): unconditional clamped reloads
  float eA[PF];
#pragma unroll
  for (int k = 0; k < PF; ++k) {
    int r = 1 + k; r = r > TT - 1 ? TT - 1 : r;
    eA[k] = lg[r * DD + jj];
  }

  auto step = [&](int t, float e) {
    // broadcast alpha to all lanes: 1 ds_write + 12 ds_read_b128 (same-addr broadcast)
    albc[j] = alpha;
    float s[DD];
    const float4* ap = (const float4*)albc;
#pragma unroll
    for (int q = 0; q < 12; ++q) {
      float4 a = ap[q];
      s[4 * q + 0] = a.x + tcol[4 * q + 0];
      s[4 * q + 1] = a.y + tcol[4 * q + 1];
      s[4 * q + 2] = a.z + tcol[4 * q + 2];
      s[4 * q + 3] = a.w + tcol[4 * q + 3];
    }
    float best; int idx;
    tree_argmax48(s, best, idx);
    alpha = best + e;                          // value chain only (no VCC)
    bp[t * STRIDE + j] = (unsigned char)idx;   // index off the critical path
  };

  int t = 1;
  while (t < L) {
#pragma unroll
    for (int k = 0; k < PF; ++k) {
      if (t >= L) break;
      step(t, eA[k]);
      int r = t + PF; r = r > TT - 1 ? TT - 1 : r;
      eA[k] = lg[r * DD + jj]; // issue now, consume PF steps later
      ++t;
    }
  }

  __syncthreads(); // single wave; ensures LDS ordering before backtrack

  // final broadcast + argmax for last_tag (all lanes uniform)
  albc[j] = alpha;
  float af[DD];
  const float4* ap = (const float4*)albc;
#pragma unroll
  for (int q = 0; q < 12; ++q) {
    float4 a = ap[q];
    af[4 * q + 0] = a.x; af[4 * q + 1] = a.y;
    af[4 * q + 2] = a.z; af[4 * q + 3] = a.w;
  }
  float bv; int btag;
  tree_argmax48(af, bv, btag);

  int* ob = out + (size_t)b * TT;
  if (j == 0) ob[L - 1] = btag;

  // Backtrack by function composition: H[j] = tag at time t given final tag j.
  int H = j;
  for (int tt = L - 1; tt >= 1; --tt) {
    int v = bp[tt * STRIDE + jj]; // addr independent of H -> pipelined
    H = __shfl(v, H, 64);         // H' = bp_t[H]
    if (j == btag) ob[tt - 1] = H;
  }

  // zero the padded tail t >= L
  for (int tt = L + j; tt < TT; tt += 64) ob[tt] = 0;
}

extern "C" void kernel_launch(void* const* d_in, const int* in_sizes, int n_in,
                              void* d_out, int out_size, void* d_ws, size_t ws_size,
                              hipStream_t stream) {
  const float* logits = (const float*)d_in[0];
  const int* lens     = (const int*)d_in[1];
  const float* trans  = (const float*)d_in[2];
  int* out            = (int*)d_out;
  (void)in_sizes; (void)n_in; (void)out_size; (void)d_ws; (void)ws_size;
  crf_viterbi<<<BB, 64, 0, stream>>>(logits, lens, trans, out);
}